// Round 4
// baseline (420.324 us; speedup 1.0000x reference)
//
#include <hip/hip_runtime.h>
#include <cstdint>
#include <cstddef>

#define E_TOT 32768
#define HD    512
#define NR    3
#define EPAD_MAX 33152          // E_TOT + 3*128
#define NBLK  259               // EPAD_MAX / 128

typedef __attribute__((ext_vector_type(8))) short short8;
typedef __attribute__((ext_vector_type(4))) float f32x4;

static __device__ __forceinline__ unsigned short f2bf(float f) {
  union { float f; unsigned int u; } x; x.f = f;
  unsigned int u = x.u;
  return (unsigned short)((u + 0x7fffu + ((u >> 16) & 1u)) >> 16);  // RNE
}
static __device__ __forceinline__ float bf2f(unsigned short h) {
  union { unsigned int u; float f; } x; x.u = ((unsigned int)h) << 16;
  return x.f;
}

static __device__ __forceinline__ void gload_lds16(const void* g, void* l) {
  __builtin_amdgcn_global_load_lds(
      (const __attribute__((address_space(1))) unsigned int*)g,
      (__attribute__((address_space(3))) unsigned int*)l, 16, 0, 0);
}

// bijective chunked XCD swizzle for NBLK=259: q=32, r=3
static __device__ __forceinline__ int chunk_swz(int bid) {
  const int xcd = bid & 7;
  const int base = (xcd < 3) ? xcd * 33 : 99 + (xcd - 3) * 32;
  return base + (bid >> 3);
}

// ---------------- prep kernels ----------------

#define AL128(x) (((x) + 127) & ~127)

__global__ void k_sort1(const int* __restrict__ roles, int* __restrict__ ctrl) {
  __shared__ int cnt[NR];
  const int t = threadIdx.x;
  if (t < NR) cnt[t] = 0;
  __syncthreads();
  int c0 = 0, c1 = 0, c2 = 0;
  for (int i = t; i < E_TOT; i += 1024) {
    const int ro = roles[i];
    c0 += (ro == 0); c1 += (ro == 1); c2 += (ro == 2);
  }
  if (c0) atomicAdd(&cnt[0], c0);
  if (c1) atomicAdd(&cnt[1], c1);
  if (c2) atomicAdd(&cnt[2], c2);
  __syncthreads();
  if (t == 0) {
    const int off1 = AL128(cnt[0]);
    const int off2 = AL128(off1 + cnt[1]);
    const int ptot = AL128(off2 + cnt[2]);
    ctrl[0] = cnt[0]; ctrl[1] = cnt[1]; ctrl[2] = cnt[2];
    ctrl[4] = 0; ctrl[5] = off1; ctrl[6] = off2; ctrl[7] = ptot;
    ctrl[9] = 0; ctrl[10] = off1; ctrl[11] = off2;
  }
}

__global__ void k_scatter(const int* __restrict__ roles, int* __restrict__ ctrl,
                          int* __restrict__ perm) {
  int e = blockIdx.x * 256 + threadIdx.x;
  int lane = threadIdx.x & 63;
  int role = roles[e];
#pragma unroll
  for (int r = 0; r < NR; ++r) {
    unsigned long long m = __ballot(role == r);
    if (!m) continue;
    int leader = __ffsll((unsigned long long)m) - 1;
    int base = 0;
    if (lane == leader) base = atomicAdd(&ctrl[9 + r], (int)__popcll(m));
    base = __shfl(base, leader);
    if (role == r) {
      int rank = (int)__popcll(m & ((1ull << lane) - 1ull));
      perm[base + rank] = e;
    }
  }
}

__global__ void k_padfill(const int* __restrict__ ctrl, int* __restrict__ perm) {
#pragma unroll
  for (int r = 0; r < NR; ++r) {
    const int start = ctrl[4 + r] + ctrl[r];
    const int end = (r < 2) ? ctrl[5 + r] : ctrl[7];
    const int fill = (ctrl[r] > 0) ? perm[ctrl[4 + r]] : 0;
    for (int i = start + (int)threadIdx.x; i < end; i += 256) perm[i] = fill;
  }
}

__global__ void k_convw(const float* __restrict__ W, const float* __restrict__ U,
                        const float* __restrict__ P1, const float* __restrict__ P2,
                        const int* __restrict__ dlayer, short* __restrict__ dst) {
  const int per = NR * HD * HD;
  const int which = blockIdx.y;
  const float* src = (which == 0) ? W : (which == 1) ? U : (which == 2) ? P1 : P2;
  src += (size_t)dlayer[0] * per;
  short* d = dst + (size_t)which * per;
  int i = (blockIdx.x * 256 + threadIdx.x) * 4;
  if (i >= per) return;
  float4 v = *(const float4*)(src + i);
  short4 o;
  o.x = (short)f2bf(v.x); o.y = (short)f2bf(v.y);
  o.z = (short)f2bf(v.z); o.w = (short)f2bf(v.w);
  *(short4*)(d + i) = o;
}

// ---------------- unified GEMM ----------------
// BM=128, BN=512 (full N), BK=32. 8 waves (2m x 4n), wave tile 64x128.
// A direct-to-register (wave-private rows); B-only LDS double buffer (2x32KB).
// Counted-vmcnt pipeline: raw s_barrier, prefetch stays in flight.
// MODE 0: out_bf16[sorted] = gatherf32(A0, perm) @ B^T + bias
// MODE 1: out_bf16[sorted] = relu((A0_bf16 * A1_bf16) @ B^T + bias)   (in-place A0 ok)
// MODE 2: out_f32[perm[row]] = A0_bf16 @ B^T + bias
template <int MODE>
__global__ __launch_bounds__(512, 2) void k_gemm(
    const void* Asrc0, const void* Asrc1,
    const short* __restrict__ Ball, const float* __restrict__ biasAll,
    const int* __restrict__ dlayer, const int* __restrict__ ctrl,
    const int* __restrict__ perm, void* outp) {
  __shared__ short lds[2][16384];   // [buf][512 rows x 32 shorts]

  const int lb = chunk_swz(blockIdx.x);
  const int m0 = lb * 128;
  if (m0 >= ctrl[7]) return;
  const int role = (m0 >= ctrl[6]) ? 2 : (m0 >= ctrl[5] ? 1 : 0);

  const int tid = threadIdx.x;
  const int lane = tid & 63;
  const int wv = tid >> 6;
  const int wr = wv >> 2, wc = wv & 3;
  const int krow = lane & 15, ku = lane >> 4;

  const short* Brole = Ball + (size_t)role * HD * HD;

  // B staging: per wave 4 x gload_lds16 covers rows wv*64..wv*64+63
  const int srow = wv * 64 + (lane >> 2);   // + c*16
  const int schunk = (lane & 3) * 8;

  // A addressing (wave-private frag rows)
  int pA[4];
  size_t arow_off[4];
  if constexpr (MODE == 0) {
#pragma unroll
    for (int mi = 0; mi < 4; ++mi)
      pA[mi] = perm[m0 + wr * 64 + mi * 16 + krow];
  } else {
#pragma unroll
    for (int mi = 0; mi < 4; ++mi)
      arow_off[mi] = (size_t)(m0 + wr * 64 + mi * 16 + krow) * HD;
  }

  f32x4 acc[4][8];
#pragma unroll
  for (int a = 0; a < 4; ++a)
#pragma unroll
    for (int b = 0; b < 8; ++b) acc[a][b] = (f32x4)0.f;

  float4 aF[2][4][2];      // MODE 0 raw f32
  short8 aV[2][4], aR[2][4];

#define BSTAGE(bi, k0_)                                                        \
  _Pragma("unroll") for (int c = 0; c < 4; ++c)                                \
    gload_lds16(Brole + (size_t)(srow + c * 16) * HD + (k0_) + schunk,         \
                (char*)&lds[bi][0] + wv * 4096 + c * 1024);

#define ALOAD(bi, k0_)                                                         \
  if constexpr (MODE == 0) {                                                   \
    _Pragma("unroll") for (int mi = 0; mi < 4; ++mi) {                         \
      const float* s = (const float*)Asrc0 + (size_t)pA[mi] * HD + (k0_) + ku * 8; \
      aF[bi][mi][0] = *(const float4*)s;                                       \
      aF[bi][mi][1] = *(const float4*)(s + 4);                                 \
    }                                                                          \
  } else if constexpr (MODE == 1) {                                            \
    _Pragma("unroll") for (int mi = 0; mi < 4; ++mi) {                         \
      aV[bi][mi] = *(const short8*)((const short*)Asrc0 + arow_off[mi] + (k0_) + ku * 8); \
      aR[bi][mi] = *(const short8*)((const short*)Asrc1 + arow_off[mi] + (k0_) + ku * 8); \
    }                                                                          \
  } else {                                                                     \
    _Pragma("unroll") for (int mi = 0; mi < 4; ++mi)                           \
      aV[bi][mi] = *(const short8*)((const short*)Asrc0 + arow_off[mi] + (k0_) + ku * 8); \
  }

  ALOAD(0, 0)
  BSTAGE(0, 0)

#pragma unroll
  for (int it = 0; it < 16; ++it) {
    const int cur = it & 1;
    if (it < 15) {
      ALOAD(1 - cur, (it + 1) * 32)
      BSTAGE(1 - cur, (it + 1) * 32)
      if constexpr (MODE == 2) {
        asm volatile("s_waitcnt vmcnt(8)" ::: "memory");
      } else {
        asm volatile("s_waitcnt vmcnt(12)" ::: "memory");
      }
    } else {
      asm volatile("s_waitcnt vmcnt(0)" ::: "memory");
    }
    __builtin_amdgcn_s_barrier();
    __builtin_amdgcn_sched_barrier(0);

    // build A fragments
    short8 fa[4];
#pragma unroll
    for (int mi = 0; mi < 4; ++mi) {
      if constexpr (MODE == 0) {
#pragma unroll
        for (int j = 0; j < 4; ++j) {
          fa[mi][j]     = (short)f2bf(aF[cur][mi][0][j]);
          fa[mi][4 + j] = (short)f2bf(aF[cur][mi][1][j]);
        }
      } else if constexpr (MODE == 1) {
#pragma unroll
        for (int j = 0; j < 8; ++j)
          fa[mi][j] = (short)f2bf(bf2f((unsigned short)aV[cur][mi][j]) *
                                  bf2f((unsigned short)aR[cur][mi][j]));
      } else {
        fa[mi] = aV[cur][mi];
      }
    }
    // B fragments from LDS
    short8 fb[8];
#pragma unroll
    for (int ni = 0; ni < 8; ++ni)
      fb[ni] = *(const short8*)&lds[cur][(wc * 128 + ni * 16 + krow) * 32 + ku * 8];
#pragma unroll
    for (int mi = 0; mi < 4; ++mi)
#pragma unroll
      for (int ni = 0; ni < 8; ++ni)
        acc[mi][ni] = __builtin_amdgcn_mfma_f32_16x16x32_bf16(fa[mi], fb[ni], acc[mi][ni], 0, 0, 0);

    __builtin_amdgcn_s_barrier();
    __builtin_amdgcn_sched_barrier(0);
  }

  const int ld = dlayer[0];
  const float* bias = biasAll + ((size_t)ld * NR + role) * HD;

  int pg[4][4];
  if constexpr (MODE == 2) {
#pragma unroll
    for (int mi = 0; mi < 4; ++mi)
#pragma unroll
      for (int j = 0; j < 4; ++j)
        pg[mi][j] = perm[m0 + wr * 64 + mi * 16 + ku * 4 + j];
  }

#pragma unroll
  for (int ni = 0; ni < 8; ++ni) {
    const int col = wc * 128 + ni * 16 + krow;
    const float b = bias[col];
#pragma unroll
    for (int mi = 0; mi < 4; ++mi) {
      const int rbase = m0 + wr * 64 + mi * 16 + ku * 4;
#pragma unroll
      for (int j = 0; j < 4; ++j) {
        float val = acc[mi][ni][j] + b;
        if constexpr (MODE == 0) {
          ((short*)outp)[(size_t)(rbase + j) * HD + col] = (short)f2bf(val);
        } else if constexpr (MODE == 1) {
          val = fmaxf(val, 0.f);
          ((short*)outp)[(size_t)(rbase + j) * HD + col] = (short)f2bf(val);
        } else {
          ((float*)outp)[(size_t)pg[mi][j] * HD + col] = val;
        }
      }
    }
  }
#undef BSTAGE
#undef ALOAD
}

// ---------------- launch ----------------

extern "C" void kernel_launch(void* const* d_in, const int* in_sizes, int n_in,
                              void* d_out, int out_size, void* d_ws, size_t ws_size,
                              hipStream_t stream) {
  const float* v    = (const float*)d_in[0];
  const float* r    = (const float*)d_in[1];
  const int*   rol  = (const int*)d_in[2];
  const float* W    = (const float*)d_in[3];
  const float* Wb   = (const float*)d_in[4];
  const float* U    = (const float*)d_in[5];
  const float* Ub   = (const float*)d_in[6];
  const float* P1   = (const float*)d_in[7];
  const float* P1b  = (const float*)d_in[8];
  const float* P2   = (const float*)d_in[9];
  const float* P2b  = (const float*)d_in[10];
  const int*   dly  = (const int*)d_in[11];

  char* ws = (char*)d_ws;
  int* ctrl = (int*)ws;                          // 256 B
  int* perm = (int*)(ws + 256);                  // EPAD_MAX ints
  short* Wbf = (short*)(ws + 132864);            // 4 x NR*HD*HD bf16 (W,U,P1,P2)
  short* Ubf  = Wbf + (size_t)NR * HD * HD;
  short* P1bf = Ubf + (size_t)NR * HD * HD;
  short* P2bf = P1bf + (size_t)NR * HD * HD;
  short* vp = (short*)(ws + 6424320);            // EPAD_MAX*HD bf16 (sorted)
  short* rp = vp + (size_t)EPAD_MAX * HD;        // EPAD_MAX*HD bf16 (sorted)
  short* tb = vp;                                // in-place: t overwrites vp per-block
  float* out = (float*)d_out;

  k_sort1<<<1, 1024, 0, stream>>>(rol, ctrl);
  k_scatter<<<E_TOT / 256, 256, 0, stream>>>(rol, ctrl, perm);
  k_padfill<<<1, 256, 0, stream>>>(ctrl, perm);
  k_convw<<<dim3((NR * HD * HD) / 4 / 256, 4, 1), 256, 0, stream>>>(W, U, P1, P2, dly, Wbf);

  k_gemm<0><<<NBLK, 512, 0, stream>>>(v, nullptr, Wbf, Wb, dly, ctrl, perm, vp);
  k_gemm<0><<<NBLK, 512, 0, stream>>>(r, nullptr, Ubf, Ub, dly, ctrl, perm, rp);
  k_gemm<1><<<NBLK, 512, 0, stream>>>(vp, rp, P1bf, P1b, dly, ctrl, perm, tb);
  k_gemm<2><<<NBLK, 512, 0, stream>>>(tb, nullptr, P2bf, P2b, dly, ctrl, perm, out);

  (void)in_sizes; (void)n_in; (void)out_size; (void)ws_size;
}

// Round 5
// 269.372 us; speedup vs baseline: 1.5604x; 1.5604x over previous
//
#include <hip/hip_runtime.h>
#include <cstdint>
#include <cstddef>

#define E_TOT 32768
#define HD    512
#define NR    3
#define EPAD_MAX 33536          // E_TOT + 3*256
#define NBLK  262               // max(131*2 for 256x256, 262 for 128-wide)

typedef __attribute__((ext_vector_type(8))) short short8;
typedef __attribute__((ext_vector_type(4))) float f32x4;

static __device__ __forceinline__ unsigned short f2bf(float f) {
  union { float f; unsigned int u; } x; x.f = f;
  unsigned int u = x.u;
  return (unsigned short)((u + 0x7fffu + ((u >> 16) & 1u)) >> 16);  // RNE
}
static __device__ __forceinline__ float bf2f(unsigned short h) {
  union { unsigned int u; float f; } x; x.u = ((unsigned int)h) << 16;
  return x.f;
}

static __device__ __forceinline__ void gload_lds16(const void* g, void* l) {
  __builtin_amdgcn_global_load_lds(
      (const __attribute__((address_space(1))) unsigned int*)g,
      (__attribute__((address_space(3))) unsigned int*)l, 16, 0, 0);
}

// bijective chunked XCD swizzle for NBLK=262: q=32, r=6
static __device__ __forceinline__ int chunk_swz(int bid) {
  const int xcd = bid & 7;
  const int base = (xcd < 6) ? xcd * 33 : 198 + (xcd - 6) * 32;
  return base + (bid >> 3);
}

// ---------------- prep kernels ----------------

#define AL256(x) (((x) + 255) & ~255)

__global__ void k_sort1(const int* __restrict__ roles, int* __restrict__ ctrl) {
  __shared__ int cnt[NR];
  const int t = threadIdx.x;
  if (t < NR) cnt[t] = 0;
  __syncthreads();
  int c0 = 0, c1 = 0, c2 = 0;
  for (int i = t; i < E_TOT; i += 1024) {
    const int ro = roles[i];
    c0 += (ro == 0); c1 += (ro == 1); c2 += (ro == 2);
  }
  if (c0) atomicAdd(&cnt[0], c0);
  if (c1) atomicAdd(&cnt[1], c1);
  if (c2) atomicAdd(&cnt[2], c2);
  __syncthreads();
  if (t == 0) {
    const int off1 = AL256(cnt[0]);
    const int off2 = AL256(off1 + cnt[1]);
    const int ptot = AL256(off2 + cnt[2]);
    ctrl[0] = cnt[0]; ctrl[1] = cnt[1]; ctrl[2] = cnt[2];
    ctrl[4] = 0; ctrl[5] = off1; ctrl[6] = off2; ctrl[7] = ptot;
    ctrl[9] = 0; ctrl[10] = off1; ctrl[11] = off2;
  }
}

__global__ void k_scatter(const int* __restrict__ roles, int* __restrict__ ctrl,
                          int* __restrict__ perm) {
  int e = blockIdx.x * 256 + threadIdx.x;
  int lane = threadIdx.x & 63;
  int role = roles[e];
#pragma unroll
  for (int r = 0; r < NR; ++r) {
    unsigned long long m = __ballot(role == r);
    if (!m) continue;
    int leader = __ffsll((unsigned long long)m) - 1;
    int base = 0;
    if (lane == leader) base = atomicAdd(&ctrl[9 + r], (int)__popcll(m));
    base = __shfl(base, leader);
    if (role == r) {
      int rank = (int)__popcll(m & ((1ull << lane) - 1ull));
      perm[base + rank] = e;
    }
  }
}

__global__ void k_padfill(const int* __restrict__ ctrl, int* __restrict__ perm) {
#pragma unroll
  for (int r = 0; r < NR; ++r) {
    const int start = ctrl[4 + r] + ctrl[r];
    const int end = (r < 2) ? ctrl[5 + r] : ctrl[7];
    const int fill = (ctrl[r] > 0) ? perm[ctrl[4 + r]] : 0;
    for (int i = start + (int)threadIdx.x; i < end; i += 256) perm[i] = fill;
  }
}

__global__ void k_convw(const float* __restrict__ W, const float* __restrict__ U,
                        const float* __restrict__ P1, const float* __restrict__ P2,
                        const int* __restrict__ dlayer, short* __restrict__ dst) {
  const int per = NR * HD * HD;
  const int which = blockIdx.y;
  const float* src = (which == 0) ? W : (which == 1) ? U : (which == 2) ? P1 : P2;
  src += (size_t)dlayer[0] * per;
  short* d = dst + (size_t)which * per;
  int i = (blockIdx.x * 256 + threadIdx.x) * 4;
  if (i >= per) return;
  float4 v = *(const float4*)(src + i);
  short4 o;
  o.x = (short)f2bf(v.x); o.y = (short)f2bf(v.y);
  o.z = (short)f2bf(v.z); o.w = (short)f2bf(v.w);
  *(short4*)(d + i) = o;
}

// ---------------- unified GEMM ----------------
// 512 threads = 8 waves (2M x 4N), BK=32, double-buffered LDS, 2-phase.
// LDS tiles [rows][32 shorts], 16B-unit XOR swizzle s' = s ^ ((row>>1)&3)
// (both-sides: pre-swizzled gload source / swizzled ds_write, XOR'd read).
// D-frag: col = lane&15, row = (lane>>4)*4 + reg  [m89/m91-verified]
//
// MODE 0: BM=256,BN=256. out_bf16[sorted] = gather_f32(A0,perm)@B^T + bias
// MODE 1: BM=128,BN=512. out_bf16[sorted] = relu((A0_bf16*A1_bf16)@B^T + bias)
//         (full-N blocks -> in-place over A0 is race-free)
// MODE 2: BM=256,BN=256. out_f32[perm[row]] = A0_bf16@B^T + bias
template <int MODE>
__global__ __launch_bounds__(512, 2) void k_gemm(
    const void* __restrict__ Asrc0, const void* __restrict__ Asrc1,
    const short* __restrict__ Ball, const float* __restrict__ biasAll,
    const int* __restrict__ dlayer, const int* __restrict__ ctrl,
    const int* __restrict__ perm, void* __restrict__ outp) {
  constexpr int BM = (MODE == 1) ? 128 : 256;
  constexpr int BN = (MODE == 1) ? 512 : 256;
  constexpr int MI = BM / 32;     // A frags per wave (wave tile BM/2 rows)
  constexpr int NI = BN / 64;     // B frags per wave (wave tile BN/4 cols)
  constexpr int ISSA = BM / 128;  // A 16B-chunks per thread
  constexpr int ISSB = BN / 128;  // B gload issues per thread

  __shared__ short As[2][BM * 32];
  __shared__ short Bs[2][BN * 32];

  const int lb = chunk_swz(blockIdx.x);
  int m0, n0;
  if constexpr (MODE == 1) { m0 = lb * 128; n0 = 0; }
  else { m0 = (lb % 131) * 256; n0 = (lb / 131) * 256; }
  if (m0 >= ctrl[7]) return;
  const int role = (m0 >= ctrl[6]) ? 2 : (m0 >= ctrl[5] ? 1 : 0);

  const int tid = threadIdx.x;
  const int lane = tid & 63;
  const int wv = tid >> 6;
  const int wr = wv >> 2, wc = wv & 3;
  const int krow = lane & 15, ku = lane >> 4;

  const short* Brole = Ball + (size_t)role * HD * HD;

  // ---- staging descriptors ----
  int grow[4], gsrc[4];                 // B gload: row + pre-swizzled src chunk (shorts)
#pragma unroll
  for (int i = 0; i < ISSB; ++i) {
    const int row = (i * 8 + wv) * 16 + (lane >> 2);
    grow[i] = row;
    gsrc[i] = ((lane & 3) ^ ((row >> 1) & 3)) * 8;
  }
  int arowS[2], acS[2], aswz[2], pA[2];     // A reg-staged (MODE 0/1)
  int a2row[2], a2src[2];                   // A gload (MODE 2)
  if constexpr (MODE != 2) {
#pragma unroll
    for (int i = 0; i < ISSA; ++i) {
      const int g = i * 512 + tid;
      arowS[i] = g >> 2;
      acS[i] = g & 3;
      aswz[i] = (acS[i] ^ ((arowS[i] >> 1) & 3)) * 8;
      if constexpr (MODE == 0) pA[i] = perm[m0 + arowS[i]];
    }
  } else {
#pragma unroll
    for (int i = 0; i < ISSA; ++i) {
      const int row = (i * 8 + wv) * 16 + (lane >> 2);
      a2row[i] = row;
      a2src[i] = ((lane & 3) ^ ((row >> 1) & 3)) * 8;
    }
  }

  f32x4 acc[MI][NI];
#pragma unroll
  for (int a = 0; a < MI; ++a)
#pragma unroll
    for (int b = 0; b < NI; ++b) acc[a][b] = (f32x4)0.f;

  float4 aF[2][2];
  short8 aV, aR;

  auto ISSUE = [&](int bi, int k0) {
    if constexpr (MODE == 0) {
#pragma unroll
      for (int i = 0; i < ISSA; ++i) {
        const float* s = (const float*)Asrc0 + (size_t)pA[i] * HD + k0 + acS[i] * 8;
        aF[i][0] = *(const float4*)s;
        aF[i][1] = *(const float4*)(s + 4);
      }
    } else if constexpr (MODE == 1) {
      aV = *(const short8*)((const short*)Asrc0 + (size_t)(m0 + arowS[0]) * HD + k0 + acS[0] * 8);
      aR = *(const short8*)((const short*)Asrc1 + (size_t)(m0 + arowS[0]) * HD + k0 + acS[0] * 8);
    } else {
#pragma unroll
      for (int i = 0; i < ISSA; ++i)
        gload_lds16((const short*)Asrc0 + (size_t)(m0 + a2row[i]) * HD + k0 + a2src[i],
                    &As[bi][(i * 8 + wv) * 512 + lane * 8]);
    }
#pragma unroll
    for (int i = 0; i < ISSB; ++i)
      gload_lds16(Brole + (size_t)(n0 + grow[i]) * HD + k0 + gsrc[i],
                  &Bs[bi][(i * 8 + wv) * 512 + lane * 8]);
  };

  auto AWRITE = [&](int bi) {
    if constexpr (MODE == 0) {
#pragma unroll
      for (int i = 0; i < ISSA; ++i) {
        short8 o;
#pragma unroll
        for (int j = 0; j < 4; ++j) {
          o[j]     = (short)f2bf(aF[i][0][j]);
          o[4 + j] = (short)f2bf(aF[i][1][j]);
        }
        *(short8*)&As[bi][arowS[i] * 32 + aswz[i]] = o;
      }
    } else if constexpr (MODE == 1) {
      short8 o;
#pragma unroll
      for (int j = 0; j < 8; ++j)
        o[j] = (short)f2bf(bf2f((unsigned short)aV[j]) * bf2f((unsigned short)aR[j]));
      *(short8*)&As[bi][arowS[0] * 32 + aswz[0]] = o;
    }
  };

  auto COMPUTE = [&](int bi) {
    short8 fa[MI], fb[NI];
#pragma unroll
    for (int mi = 0; mi < MI; ++mi) {
      const int rr = wr * (MI * 16) + mi * 16 + krow;
      fa[mi] = *(const short8*)&As[bi][rr * 32 + (ku ^ ((rr >> 1) & 3)) * 8];
    }
#pragma unroll
    for (int ni = 0; ni < NI; ++ni) {
      const int rr = wc * (NI * 16) + ni * 16 + krow;
      fb[ni] = *(const short8*)&Bs[bi][rr * 32 + (ku ^ ((rr >> 1) & 3)) * 8];
    }
#pragma unroll
    for (int mi = 0; mi < MI; ++mi)
#pragma unroll
      for (int ni = 0; ni < NI; ++ni)
        acc[mi][ni] = __builtin_amdgcn_mfma_f32_16x16x32_bf16(fa[mi], fb[ni], acc[mi][ni], 0, 0, 0);
  };

  ISSUE(0, 0);
  if constexpr (MODE != 2) AWRITE(0);
  __syncthreads();
  for (int it = 0; it < 16; ++it) {
    const int cur = it & 1;
    if (it < 15) ISSUE(cur ^ 1, (it + 1) * 32);   // loads in flight during compute
    COMPUTE(cur);
    if (it < 15) { if constexpr (MODE != 2) AWRITE(cur ^ 1); }
    __syncthreads();
  }

  const int ld = dlayer[0];
  const float* bias = biasAll + ((size_t)ld * NR + role) * HD + n0;

  int pg[MI][4];
  if constexpr (MODE == 2) {
#pragma unroll
    for (int mi = 0; mi < MI; ++mi)
#pragma unroll
      for (int j = 0; j < 4; ++j)
        pg[mi][j] = perm[m0 + wr * (MI * 16) + mi * 16 + ku * 4 + j];
  }

#pragma unroll
  for (int ni = 0; ni < NI; ++ni) {
    const int col = wc * (NI * 16) + ni * 16 + krow;
    const float b = bias[col];
#pragma unroll
    for (int mi = 0; mi < MI; ++mi) {
      const int rbase = m0 + wr * (MI * 16) + mi * 16 + ku * 4;
#pragma unroll
      for (int j = 0; j < 4; ++j) {
        float val = acc[mi][ni][j] + b;
        if constexpr (MODE == 0) {
          ((short*)outp)[(size_t)(rbase + j) * HD + n0 + col] = (short)f2bf(val);
        } else if constexpr (MODE == 1) {
          val = fmaxf(val, 0.f);
          ((short*)outp)[(size_t)(rbase + j) * HD + col] = (short)f2bf(val);
        } else {
          ((float*)outp)[(size_t)pg[mi][j] * HD + n0 + col] = val;
        }
      }
    }
  }
}

// ---------------- launch ----------------

extern "C" void kernel_launch(void* const* d_in, const int* in_sizes, int n_in,
                              void* d_out, int out_size, void* d_ws, size_t ws_size,
                              hipStream_t stream) {
  const float* v    = (const float*)d_in[0];
  const float* r    = (const float*)d_in[1];
  const int*   rol  = (const int*)d_in[2];
  const float* W    = (const float*)d_in[3];
  const float* Wb   = (const float*)d_in[4];
  const float* U    = (const float*)d_in[5];
  const float* Ub   = (const float*)d_in[6];
  const float* P1   = (const float*)d_in[7];
  const float* P1b  = (const float*)d_in[8];
  const float* P2   = (const float*)d_in[9];
  const float* P2b  = (const float*)d_in[10];
  const int*   dly  = (const int*)d_in[11];

  char* ws = (char*)d_ws;
  int* ctrl = (int*)ws;                          // 256 B
  int* perm = (int*)(ws + 256);                  // EPAD_MAX ints (134144 B)
  short* Wbf = (short*)(ws + 134400);            // 4 x NR*HD*HD bf16 (W,U,P1,P2)
  short* Ubf  = Wbf + (size_t)NR * HD * HD;
  short* P1bf = Ubf + (size_t)NR * HD * HD;
  short* P2bf = P1bf + (size_t)NR * HD * HD;
  short* vp = (short*)(ws + 6425856);            // EPAD_MAX*HD bf16 (sorted)
  short* rp = vp + (size_t)EPAD_MAX * HD;        // EPAD_MAX*HD bf16 (sorted)
  short* tb = vp;                                // in-place: t overwrites vp (full-N G2)
  float* out = (float*)d_out;

  k_sort1<<<1, 1024, 0, stream>>>(rol, ctrl);
  k_scatter<<<E_TOT / 256, 256, 0, stream>>>(rol, ctrl, perm);
  k_padfill<<<1, 256, 0, stream>>>(ctrl, perm);
  k_convw<<<dim3((NR * HD * HD) / 4 / 256, 4, 1), 256, 0, stream>>>(W, U, P1, P2, dly, Wbf);

  k_gemm<0><<<NBLK, 512, 0, stream>>>(v, nullptr, Wbf, Wb, dly, ctrl, perm, vp);
  k_gemm<0><<<NBLK, 512, 0, stream>>>(r, nullptr, Ubf, Ub, dly, ctrl, perm, rp);
  k_gemm<1><<<NBLK, 512, 0, stream>>>(vp, rp, P1bf, P1b, dly, ctrl, perm, tb);
  k_gemm<2><<<NBLK, 512, 0, stream>>>(tb, nullptr, P2bf, P2b, dly, ctrl, perm, out);

  (void)in_sizes; (void)n_in; (void)out_size; (void)ws_size;
}

// Round 6
// 257.648 us; speedup vs baseline: 1.6314x; 1.0455x over previous
//
#include <hip/hip_runtime.h>
#include <cstdint>
#include <cstddef>

#define E_TOT 32768
#define HD    512
#define NR    3
#define EPAD_MAX 32960          // E_TOT + 3*64
#define NB1   515               // EPAD_MAX / 64
#define NB0   1030              // 2 matrices

typedef __attribute__((ext_vector_type(8))) short short8;
typedef __attribute__((ext_vector_type(4))) float f32x4;

static __device__ __forceinline__ unsigned short f2bf(float f) {
  union { float f; unsigned int u; } x; x.f = f;
  unsigned int u = x.u;
  return (unsigned short)((u + 0x7fffu + ((u >> 16) & 1u)) >> 16);  // RNE
}
static __device__ __forceinline__ float bf2f(unsigned short h) {
  union { unsigned int u; float f; } x; x.u = ((unsigned int)h) << 16;
  return x.f;
}

static __device__ __forceinline__ void gload_lds16(const void* g, void* l) {
  __builtin_amdgcn_global_load_lds(
      (const __attribute__((address_space(1))) unsigned int*)g,
      (__attribute__((address_space(3))) unsigned int*)l, 16, 0, 0);
}

// bijective chunked XCD swizzle (m204): each XCD gets a contiguous range
template <int NWG>
static __device__ __forceinline__ int chunk_swz(int bid) {
  constexpr int q = NWG / 8, rr = NWG % 8;
  const int xcd = bid & 7;
  const int idx = bid >> 3;
  return (xcd < rr) ? (xcd * (q + 1) + idx)
                    : (rr * (q + 1) + (xcd - rr) * q + idx);
}

// ---------------- prep kernels ----------------

#define AL64(x) (((x) + 63) & ~63)

__global__ void k_sort1(const int* __restrict__ roles, int* __restrict__ ctrl) {
  __shared__ int cnt[NR];
  const int t = threadIdx.x;
  if (t < NR) cnt[t] = 0;
  __syncthreads();
  int c0 = 0, c1 = 0, c2 = 0;
  for (int i = t; i < E_TOT; i += 1024) {
    const int ro = roles[i];
    c0 += (ro == 0); c1 += (ro == 1); c2 += (ro == 2);
  }
  if (c0) atomicAdd(&cnt[0], c0);
  if (c1) atomicAdd(&cnt[1], c1);
  if (c2) atomicAdd(&cnt[2], c2);
  __syncthreads();
  if (t == 0) {
    const int off1 = AL64(cnt[0]);
    const int off2 = AL64(off1 + cnt[1]);
    const int ptot = AL64(off2 + cnt[2]);
    ctrl[0] = cnt[0]; ctrl[1] = cnt[1]; ctrl[2] = cnt[2];
    ctrl[4] = 0; ctrl[5] = off1; ctrl[6] = off2; ctrl[7] = ptot;
    ctrl[9] = 0; ctrl[10] = off1; ctrl[11] = off2;
  }
}

__global__ void k_scatter(const int* __restrict__ roles, int* __restrict__ ctrl,
                          int* __restrict__ perm) {
  int e = blockIdx.x * 256 + threadIdx.x;
  int lane = threadIdx.x & 63;
  int role = roles[e];
#pragma unroll
  for (int r = 0; r < NR; ++r) {
    unsigned long long m = __ballot(role == r);
    if (!m) continue;
    int leader = __ffsll((unsigned long long)m) - 1;
    int base = 0;
    if (lane == leader) base = atomicAdd(&ctrl[9 + r], (int)__popcll(m));
    base = __shfl(base, leader);
    if (role == r) {
      int rank = (int)__popcll(m & ((1ull << lane) - 1ull));
      perm[base + rank] = e;
    }
  }
}

__global__ void k_padfill(const int* __restrict__ ctrl, int* __restrict__ perm) {
#pragma unroll
  for (int r = 0; r < NR; ++r) {
    const int start = ctrl[4 + r] + ctrl[r];
    const int end = (r < 2) ? ctrl[5 + r] : ctrl[7];
    const int fill = (ctrl[r] > 0) ? perm[ctrl[4 + r]] : 0;
    for (int i = start + (int)threadIdx.x; i < end; i += 256) perm[i] = fill;
  }
}

__global__ void k_convw(const float* __restrict__ W, const float* __restrict__ U,
                        const float* __restrict__ P1, const float* __restrict__ P2,
                        const int* __restrict__ dlayer, short* __restrict__ dst) {
  const int per = NR * HD * HD;
  const int which = blockIdx.y;
  const float* src = (which == 0) ? W : (which == 1) ? U : (which == 2) ? P1 : P2;
  src += (size_t)dlayer[0] * per;
  short* d = dst + (size_t)which * per;
  int i = (blockIdx.x * 256 + threadIdx.x) * 4;
  if (i >= per) return;
  float4 v = *(const float4*)(src + i);
  short4 o;
  o.x = (short)f2bf(v.x); o.y = (short)f2bf(v.y);
  o.z = (short)f2bf(v.z); o.w = (short)f2bf(v.w);
  *(short4*)(d + i) = o;
}

// ---------------- unified GEMM ----------------
// BM=64, BN=512 (full N), BK=32. 512 threads = 8 waves (2M x 4N),
// wave tile 32x128. Double-buffered LDS (72KB), one barrier per K-step.
// 16B-unit XOR swizzle s' = s ^ ((row>>1)&3), both-sides (verified 0-conflict R5).
// D-frag: col = lane&15, row = (lane>>4)*4 + reg  [m89/m91-verified]
//
// MODE 0 (grid 1030, pair=bid>=515 selects {v,W,Wb,vp} vs {r,U,Ub,rp}):
//         out_bf16[sorted] = gather_f32(A,perm)@B^T + bias
// MODE 1 (grid 515): out_bf16[sorted] = relu((vp*rp)@B^T + bias), in-place over vp
// MODE 2 (grid 515): out_f32[perm[row]] = A_bf16@B^T + bias
template <int MODE>
__global__ __launch_bounds__(512, 4) void k_gemm(
    const void* __restrict__ A0, const void* __restrict__ A1,
    const short* __restrict__ B0, const short* __restrict__ B1,
    const float* __restrict__ bias0, const float* __restrict__ bias1,
    const int* __restrict__ dlayer, const int* __restrict__ ctrl,
    const int* __restrict__ perm, void* __restrict__ out0,
    void* __restrict__ out1) {
  __shared__ short As[2][64 * 32];
  __shared__ short Bs[2][512 * 32];

  int lb = chunk_swz<(MODE == 0) ? NB0 : NB1>(blockIdx.x);
  int pair = 0;
  if constexpr (MODE == 0) {
    pair = lb >= NB1;
    lb -= pair * NB1;
  }
  const int m0 = lb * 64;
  if (m0 >= ctrl[7]) return;
  const int role = (m0 >= ctrl[6]) ? 2 : (m0 >= ctrl[5] ? 1 : 0);

  const int tid = threadIdx.x;
  const int lane = tid & 63;
  const int wv = tid >> 6;
  const int wr = wv >> 2, wc = wv & 3;   // 2M x 4N waves
  const int krow = lane & 15, ku = lane >> 4;

  const short* Brole = ((MODE == 0 && pair) ? B1 : B0) + (size_t)role * HD * HD;
  const float* af32 = (const float*)((MODE == 0 && pair) ? A1 : A0);

  // B staging: 4 x gload_lds16 per thread, rows i*128 + wv*16 + (lane>>2)
  int brow[4], bsrc[4];
#pragma unroll
  for (int i = 0; i < 4; ++i) {
    const int row = i * 128 + wv * 16 + (lane >> 2);
    brow[i] = row;
    bsrc[i] = ((lane & 3) ^ ((row >> 1) & 3)) * 8;
  }
  // A staging: threads 0..255 cover 64 rows x 32 k (one 16B chunk each)
  const int arow = tid >> 2;            // 0..63 (tid<256)
  const int ac = tid & 3;
  const int aswz = (ac ^ ((arow >> 1) & 3)) * 8;
  int pA = 0;
  if constexpr (MODE == 0) {
    if (tid < 256) pA = perm[m0 + arow];
  }

  f32x4 acc[2][8];
#pragma unroll
  for (int a = 0; a < 2; ++a)
#pragma unroll
    for (int b = 0; b < 8; ++b) acc[a][b] = (f32x4)0.f;

  float4 aF0, aF1;
  short8 aV, aR;

  auto ISSUE = [&](int bi, int k0) {
    if constexpr (MODE == 0) {
      if (tid < 256) {
        const float* s = af32 + (size_t)pA * HD + k0 + ac * 8;
        aF0 = *(const float4*)s;
        aF1 = *(const float4*)(s + 4);
      }
    } else if constexpr (MODE == 1) {
      if (tid < 256) {
        aV = *(const short8*)((const short*)A0 + (size_t)(m0 + arow) * HD + k0 + ac * 8);
        aR = *(const short8*)((const short*)A1 + (size_t)(m0 + arow) * HD + k0 + ac * 8);
      }
    } else {
      if (tid < 256)
        gload_lds16((const short*)A0 + (size_t)(m0 + arow) * HD + k0 + aswz,
                    &As[bi][tid * 8]);
    }
#pragma unroll
    for (int i = 0; i < 4; ++i)
      gload_lds16(Brole + (size_t)brow[i] * HD + k0 + bsrc[i],
                  &Bs[bi][(i * 8 + wv) * 512 + lane * 8]);
  };

  auto AWRITE = [&](int bi) {
    if (tid < 256) {
      short8 o;
      if constexpr (MODE == 0) {
#pragma unroll
        for (int j = 0; j < 4; ++j) {
          o[j]     = (short)f2bf(aF0[j]);
          o[4 + j] = (short)f2bf(aF1[j]);
        }
      } else {
#pragma unroll
        for (int j = 0; j < 8; ++j)
          o[j] = (short)f2bf(bf2f((unsigned short)aV[j]) *
                             bf2f((unsigned short)aR[j]));
      }
      *(short8*)&As[bi][arow * 32 + aswz] = o;
    }
  };

  auto COMPUTE = [&](int bi) {
    short8 fa[2], fb[8];
#pragma unroll
    for (int mi = 0; mi < 2; ++mi) {
      const int rr = wr * 32 + mi * 16 + krow;
      fa[mi] = *(const short8*)&As[bi][rr * 32 + (ku ^ ((rr >> 1) & 3)) * 8];
    }
#pragma unroll
    for (int ni = 0; ni < 8; ++ni) {
      const int rr = wc * 128 + ni * 16 + krow;
      fb[ni] = *(const short8*)&Bs[bi][rr * 32 + (ku ^ ((rr >> 1) & 3)) * 8];
    }
#pragma unroll
    for (int mi = 0; mi < 2; ++mi)
#pragma unroll
      for (int ni = 0; ni < 8; ++ni)
        acc[mi][ni] = __builtin_amdgcn_mfma_f32_16x16x32_bf16(fa[mi], fb[ni], acc[mi][ni], 0, 0, 0);
  };

  ISSUE(0, 0);
  if constexpr (MODE != 2) AWRITE(0);
  __syncthreads();
  for (int it = 0; it < 16; ++it) {
    const int cur = it & 1;
    if (it < 15) ISSUE(cur ^ 1, (it + 1) * 32);   // loads in flight under compute
    COMPUTE(cur);
    if constexpr (MODE != 2) {
      if (it < 15) AWRITE(cur ^ 1);
    }
    __syncthreads();
  }

  const int ld = dlayer[0];
  const float* bias = ((MODE == 0 && pair) ? bias1 : bias0) +
                      ((size_t)ld * NR + role) * HD;
  short* outb = (short*)((MODE == 0 && pair) ? out1 : out0);

  int pg[2][4];
  if constexpr (MODE == 2) {
#pragma unroll
    for (int mi = 0; mi < 2; ++mi)
#pragma unroll
      for (int j = 0; j < 4; ++j)
        pg[mi][j] = perm[m0 + wr * 32 + mi * 16 + ku * 4 + j];
  }

#pragma unroll
  for (int ni = 0; ni < 8; ++ni) {
    const int col = wc * 128 + ni * 16 + krow;
    const float b = bias[col];
#pragma unroll
    for (int mi = 0; mi < 2; ++mi) {
      const int rbase = m0 + wr * 32 + mi * 16 + ku * 4;
#pragma unroll
      for (int j = 0; j < 4; ++j) {
        float val = acc[mi][ni][j] + b;
        if constexpr (MODE == 0) {
          outb[(size_t)(rbase + j) * HD + col] = (short)f2bf(val);
        } else if constexpr (MODE == 1) {
          val = fmaxf(val, 0.f);
          outb[(size_t)(rbase + j) * HD + col] = (short)f2bf(val);
        } else {
          ((float*)out0)[(size_t)pg[mi][j] * HD + col] = val;
        }
      }
    }
  }
}

// ---------------- launch ----------------

extern "C" void kernel_launch(void* const* d_in, const int* in_sizes, int n_in,
                              void* d_out, int out_size, void* d_ws, size_t ws_size,
                              hipStream_t stream) {
  const float* v    = (const float*)d_in[0];
  const float* r    = (const float*)d_in[1];
  const int*   rol  = (const int*)d_in[2];
  const float* W    = (const float*)d_in[3];
  const float* Wb   = (const float*)d_in[4];
  const float* U    = (const float*)d_in[5];
  const float* Ub   = (const float*)d_in[6];
  const float* P1   = (const float*)d_in[7];
  const float* P1b  = (const float*)d_in[8];
  const float* P2   = (const float*)d_in[9];
  const float* P2b  = (const float*)d_in[10];
  const int*   dly  = (const int*)d_in[11];

  char* ws = (char*)d_ws;
  int* ctrl = (int*)ws;                          // 256 B
  int* perm = (int*)(ws + 256);                  // EPAD_MAX ints -> ends 132096
  short* Wbf = (short*)(ws + 132096);            // 4 x NR*HD*HD bf16 (W,U,P1,P2)
  short* Ubf  = Wbf + (size_t)NR * HD * HD;
  short* P1bf = Ubf + (size_t)NR * HD * HD;
  short* P2bf = P1bf + (size_t)NR * HD * HD;
  short* vp = (short*)(ws + 6423552);            // EPAD_MAX*HD bf16 (sorted)
  short* rp = vp + (size_t)EPAD_MAX * HD;        // EPAD_MAX*HD bf16 (sorted)
  short* tb = vp;                                // in-place: t over vp (full-N blocks)
  float* out = (float*)d_out;

  k_sort1<<<1, 1024, 0, stream>>>(rol, ctrl);
  k_scatter<<<E_TOT / 256, 256, 0, stream>>>(rol, ctrl, perm);
  k_padfill<<<1, 256, 0, stream>>>(ctrl, perm);
  k_convw<<<dim3((NR * HD * HD) / 4 / 256, 4, 1), 256, 0, stream>>>(W, U, P1, P2, dly, Wbf);

  k_gemm<0><<<NB0, 512, 0, stream>>>(v, r, Wbf, Ubf, Wb, Ub, dly, ctrl, perm, vp, rp);
  k_gemm<1><<<NB1, 512, 0, stream>>>(vp, rp, P1bf, nullptr, P1b, nullptr, dly, ctrl, perm, tb, nullptr);
  k_gemm<2><<<NB1, 512, 0, stream>>>(tb, nullptr, P2bf, nullptr, P2b, nullptr, dly, ctrl, perm, out, nullptr);

  (void)in_sizes; (void)n_in; (void)out_size; (void)ws_size;
}

// Round 7
// 237.238 us; speedup vs baseline: 1.7717x; 1.0860x over previous
//
#include <hip/hip_runtime.h>
#include <cstdint>
#include <cstddef>

#define E_TOT 32768
#define HD    512
#define NR    3
#define EPAD_MAX 33536          // E_TOT + 3*256
#define NB_M  131               // EPAD_MAX / 256
#define NBG1  262               // NB_M * 2 N-tiles
#define NBG0  524               // 2 matrices

typedef __attribute__((ext_vector_type(8))) short short8;
typedef __attribute__((ext_vector_type(4))) float f32x4;

static __device__ __forceinline__ unsigned short f2bf(float f) {
  union { float f; unsigned int u; } x; x.f = f;
  unsigned int u = x.u;
  return (unsigned short)((u + 0x7fffu + ((u >> 16) & 1u)) >> 16);  // RNE
}
static __device__ __forceinline__ float bf2f(unsigned short h) {
  union { unsigned int u; float f; } x; x.u = ((unsigned int)h) << 16;
  return x.f;
}

static __device__ __forceinline__ void gload_lds16(const void* g, void* l) {
  __builtin_amdgcn_global_load_lds(
      (const __attribute__((address_space(1))) unsigned int*)g,
      (__attribute__((address_space(3))) unsigned int*)l, 16, 0, 0);
}

// bijective chunked XCD swizzle (m204)
template <int NWG>
static __device__ __forceinline__ int chunk_swz(int bid) {
  constexpr int q = NWG / 8, r = NWG % 8;
  const int x = bid & 7, i = bid >> 3;
  return (x < r) ? x * (q + 1) + i : r * (q + 1) + (x - r) * q + i;
}

// ---------------- prep kernels ----------------

#define AL256(x) (((x) + 255) & ~255)

__global__ void k_sort1(const int* __restrict__ roles, int* __restrict__ ctrl) {
  __shared__ int cnt[NR];
  const int t = threadIdx.x;
  if (t < NR) cnt[t] = 0;
  __syncthreads();
  int c0 = 0, c1 = 0, c2 = 0;
  for (int i = t; i < E_TOT; i += 1024) {
    const int ro = roles[i];
    c0 += (ro == 0); c1 += (ro == 1); c2 += (ro == 2);
  }
  if (c0) atomicAdd(&cnt[0], c0);
  if (c1) atomicAdd(&cnt[1], c1);
  if (c2) atomicAdd(&cnt[2], c2);
  __syncthreads();
  if (t == 0) {
    const int off1 = AL256(cnt[0]);
    const int off2 = AL256(off1 + cnt[1]);
    const int ptot = AL256(off2 + cnt[2]);
    ctrl[0] = cnt[0]; ctrl[1] = cnt[1]; ctrl[2] = cnt[2];
    ctrl[4] = 0; ctrl[5] = off1; ctrl[6] = off2; ctrl[7] = ptot;
    ctrl[9] = 0; ctrl[10] = off1; ctrl[11] = off2;
  }
}

__global__ void k_scatter(const int* __restrict__ roles, int* __restrict__ ctrl,
                          int* __restrict__ perm) {
  int e = blockIdx.x * 256 + threadIdx.x;
  int lane = threadIdx.x & 63;
  int role = roles[e];
#pragma unroll
  for (int r = 0; r < NR; ++r) {
    unsigned long long m = __ballot(role == r);
    if (!m) continue;
    int leader = __ffsll((unsigned long long)m) - 1;
    int base = 0;
    if (lane == leader) base = atomicAdd(&ctrl[9 + r], (int)__popcll(m));
    base = __shfl(base, leader);
    if (role == r) {
      int rank = (int)__popcll(m & ((1ull << lane) - 1ull));
      perm[base + rank] = e;
    }
  }
}

__global__ void k_padfill(const int* __restrict__ ctrl, int* __restrict__ perm) {
#pragma unroll
  for (int r = 0; r < NR; ++r) {
    const int start = ctrl[4 + r] + ctrl[r];
    const int end = (r < 2) ? ctrl[5 + r] : ctrl[7];
    const int fill = (ctrl[r] > 0) ? perm[ctrl[4 + r]] : 0;
    for (int i = start + (int)threadIdx.x; i < end; i += 256) perm[i] = fill;
  }
}

__global__ void k_convw(const float* __restrict__ W, const float* __restrict__ U,
                        const float* __restrict__ P1, const float* __restrict__ P2,
                        const int* __restrict__ dlayer, short* __restrict__ dst) {
  const int per = NR * HD * HD;
  const int which = blockIdx.y;
  const float* src = (which == 0) ? W : (which == 1) ? U : (which == 2) ? P1 : P2;
  src += (size_t)dlayer[0] * per;
  short* d = dst + (size_t)which * per;
  int i = (blockIdx.x * 256 + threadIdx.x) * 4;
  if (i >= per) return;
  float4 v = *(const float4*)(src + i);
  short4 o;
  o.x = (short)f2bf(v.x); o.y = (short)f2bf(v.y);
  o.z = (short)f2bf(v.z); o.w = (short)f2bf(v.w);
  *(short4*)(d + i) = o;
}

// fallback final scatter (only when ws is small)
__global__ void k_unsort(const float* __restrict__ outs, const int* __restrict__ perm,
                         const int* __restrict__ ctrl, float* __restrict__ out) {
  const int idx = blockIdx.x * 256 + threadIdx.x;
  const int row = idx >> 7, c4 = (idx & 127) << 2;
  if (row >= ctrl[7]) return;
  float4 v = *(const float4*)(outs + (size_t)row * HD + c4);
  *(float4*)(out + (size_t)perm[row] * HD + c4) = v;
}

// ---------------- 4-phase pipelined GEMM ----------------
// BM=BN=256, BK=64, 512 thr = 8 waves (2M x 4N), wave tile 128x64.
// LDS 128KB: [slot 0/1][A 2048 units | B 2048 units], unit = 8 bf16 (16B).
// Unit layout: g = half*1024 + (row&127)*8 + (u ^ (row&7))  [XOR swizzle].
// Schedule per K-tile t (slot cur=t&1): P0 reads B-frags+A-q0, issues A(t+1);
// P1/P2 read A-q1/q2, stage B(t+2) halves into cur (B LDS dead after P0);
// P3 reads A-q3, writes A(t+1) to cur^1, vmcnt(4) [never 0 mid-loop].
// D-frag: col = lane&15, row = (lane>>4)*4 + reg  [m89/m91-verified]
//
// MODE 0: pair selects {v,W,Wb}->vp / {r,U,Ub}->rp; gather f32 via perm, fused cvt.
// MODE 1: A = vp*rp elementwise (in-register), relu epilogue -> tb bf16.
// MODE 2: A = tb bf16 via global_load_lds; f32 out (scat: via perm, else sorted).
template <int MODE>
__global__ __launch_bounds__(512, 2) void k_gemm(
    const void* __restrict__ A0v, const void* __restrict__ A1v,
    const short* __restrict__ B0, const short* __restrict__ B1,
    const float* __restrict__ bias0, const float* __restrict__ bias1,
    const int* __restrict__ dlayer, const int* __restrict__ ctrl,
    const int* __restrict__ perm, float* __restrict__ outF,
    short* __restrict__ outS0, short* __restrict__ outS1, int scat) {
  __shared__ short8 lds8[2][4096];   // 128 KB

  int lb = chunk_swz<(MODE == 0) ? NBG0 : NBG1>(blockIdx.x);
  int pair = 0;
  if constexpr (MODE == 0) { pair = lb >= NBG1 ? 1 : 0; lb -= pair * NBG1; }
  const int mt = lb >> 1, nt = lb & 1;
  const int m0 = mt * 256, n0 = nt * 256;
  if (m0 >= ctrl[7]) return;
  const int role = (m0 >= ctrl[6]) ? 2 : (m0 >= ctrl[5] ? 1 : 0);

  const int tid = threadIdx.x;
  const int lane = tid & 63;
  const int wv = tid >> 6;
  const int wr = wv >> 2, wc = wv & 3;
  const int krow = lane & 15, ku = lane >> 4;

  const short* Brole = ((MODE == 0 && pair) ? B1 : B0) + (size_t)role * HD * HD;
  const float* af32 = (const float*)((MODE == 0 && pair) ? A1v : A0v);
  const short* Abf  = (const short*)A0v;    // MODE2
  const short* vpA  = (const short*)A0v;    // MODE1
  const short* rpA  = (const short*)A1v;    // MODE1

  // B stage source offsets (elements, without k0); g = j*512+tid
  unsigned bsrc[4];
#pragma unroll
  for (int j = 0; j < 4; ++j) {
    const int g = j * 512 + tid;
    const int u = (g & 7) ^ ((g >> 3) & 7);
    bsrc[j] = (unsigned)(n0 + (g >> 3)) * HD + u * 8;
  }
  // A stage descriptors
  unsigned asrc[4];                    // MODE2 gload
  unsigned aoff[4];                    // MODE0/1 reg-stage row offsets
  const int uA = ((tid & 7) ^ ((tid >> 3) & 7)) * 8;   // fixed k-unit (elems)
  if constexpr (MODE == 2) {
#pragma unroll
    for (int j = 0; j < 4; ++j) {
      const int g = j * 512 + tid;
      const int u = (g & 7) ^ ((g >> 3) & 7);
      asrc[j] = (unsigned)(m0 + (g >> 3)) * HD + u * 8;
    }
  } else if constexpr (MODE == 0) {
#pragma unroll
    for (int i = 0; i < 4; ++i)
      aoff[i] = (unsigned)perm[m0 + (tid >> 3) + i * 64] * HD + uA;
  } else {
#pragma unroll
    for (int i = 0; i < 4; ++i)
      aoff[i] = (unsigned)(m0 + (tid >> 3) + i * 64) * HD + uA;
  }

  // fragment LDS indices
  int kx[2];
#pragma unroll
  for (int ks = 0; ks < 2; ++ks) kx[ks] = (ks * 4 + ku) ^ (krow & 7);
  const int gA = wr * 1024 + krow * 8;
  const int gB = 2048 + (wc >> 1) * 1024 + ((wc & 1) * 64 + krow) * 8;

  f32x4 acc[8][4];
#pragma unroll
  for (int a = 0; a < 8; ++a)
#pragma unroll
    for (int b = 0; b < 4; ++b) acc[a][b] = (f32x4)0.f;

  float4 af[4][2];
  short8 av[4], ar[4];
  short8 fa[2][2], fb[4][2];

#define ISSUE_A(K0)                                                            \
  if constexpr (MODE == 0) {                                                   \
    _Pragma("unroll") for (int i = 0; i < 4; ++i) {                            \
      const float* s = af32 + (size_t)aoff[i] + (K0);                          \
      af[i][0] = *(const float4*)s;                                            \
      af[i][1] = *(const float4*)(s + 4);                                      \
    }                                                                          \
  } else if constexpr (MODE == 1) {                                            \
    _Pragma("unroll") for (int i = 0; i < 4; ++i) {                            \
      av[i] = *(const short8*)(vpA + (size_t)aoff[i] + (K0));                  \
      ar[i] = *(const short8*)(rpA + (size_t)aoff[i] + (K0));                  \
    }                                                                          \
  } else {                                                                     \
    _Pragma("unroll") for (int j = 0; j < 4; ++j)                              \
      gload_lds16(Abf + (size_t)asrc[j] + (K0), Ln + j * 512 + tid);           \
  }

#define WRITE_A()                                                              \
  if constexpr (MODE == 0) {                                                   \
    _Pragma("unroll") for (int i = 0; i < 4; ++i) {                            \
      short8 o;                                                                \
      _Pragma("unroll") for (int j = 0; j < 4; ++j) {                          \
        o[j] = (short)f2bf(af[i][0][j]);                                       \
        o[4 + j] = (short)f2bf(af[i][1][j]);                                   \
      }                                                                        \
      Ln[i * 512 + tid] = o;                                                   \
    }                                                                          \
  } else if constexpr (MODE == 1) {                                            \
    _Pragma("unroll") for (int i = 0; i < 4; ++i) {                            \
      short8 o;                                                                \
      _Pragma("unroll") for (int j = 0; j < 8; ++j)                            \
        o[j] = (short)f2bf(bf2f((unsigned short)av[i][j]) *                    \
                           bf2f((unsigned short)ar[i][j]));                    \
      Ln[i * 512 + tid] = o;                                                   \
    }                                                                          \
  }

#define STAGE_B(JB, K0)                                                        \
  _Pragma("unroll") for (int j = JB; j < (JB) + 2; ++j)                        \
    gload_lds16(Brole + (size_t)bsrc[j] + (K0), Lc + 2048 + j * 512 + tid);

#define READ_FA(MI0)                                                           \
  _Pragma("unroll") for (int mi = 0; mi < 2; ++mi)                             \
    _Pragma("unroll") for (int ks = 0; ks < 2; ++ks)                           \
      fa[mi][ks] = Lc[gA + ((MI0) + mi) * 128 + kx[ks]];

#define PHASE_TAIL(MI0)                                                        \
  __builtin_amdgcn_s_barrier();                                                \
  asm volatile("s_waitcnt lgkmcnt(0)" ::: "memory");                           \
  __builtin_amdgcn_sched_barrier(0);                                           \
  __builtin_amdgcn_s_setprio(1);                                               \
  _Pragma("unroll") for (int ks = 0; ks < 2; ++ks)                             \
    _Pragma("unroll") for (int mi = 0; mi < 2; ++mi)                           \
      _Pragma("unroll") for (int ni = 0; ni < 4; ++ni)                         \
        acc[(MI0) + mi][ni] = __builtin_amdgcn_mfma_f32_16x16x32_bf16(         \
            fa[mi][ks], fb[ni][ks], acc[(MI0) + mi][ni], 0, 0, 0);             \
  __builtin_amdgcn_s_setprio(0);                                               \
  __builtin_amdgcn_s_barrier();

  // ---- prologue: A(0), B(0) -> slot0, B(1) -> slot1 ----
  {
    short8* Ln = &lds8[0][0];
    short8* Lc = &lds8[0][0];
    ISSUE_A(0)
    STAGE_B(0, 0) STAGE_B(2, 0)
    Lc = &lds8[1][0];
    STAGE_B(0, 64) STAGE_B(2, 64)
    asm volatile("s_waitcnt vmcnt(4)" ::: "memory");
    WRITE_A()
    asm volatile("s_waitcnt lgkmcnt(0)" ::: "memory");
    __builtin_amdgcn_s_barrier();
  }

  int cur = 0;
  for (int t = 0; t < 8; ++t) {
    short8* Lc = &lds8[cur][0];
    short8* Ln = &lds8[cur ^ 1][0];
    const int k0a = (t + 1) * 64;
    const int k0b = (t + 2) * 64;

    // P0: B-frags + A q0; issue next A
#pragma unroll
    for (int ni = 0; ni < 4; ++ni)
#pragma unroll
      for (int ks = 0; ks < 2; ++ks)
        fb[ni][ks] = Lc[gB + ni * 128 + kx[ks]];
    READ_FA(0)
    if (t < 7) { ISSUE_A(k0a) }
    PHASE_TAIL(0)

    // P1: A q1; stage B_lo(t+2) into cur
    READ_FA(2)
    if (t < 6) { STAGE_B(0, k0b) }
    PHASE_TAIL(2)

    // P2: A q2; stage B_hi(t+2) into cur
    READ_FA(4)
    if (t < 6) { STAGE_B(2, k0b) }
    PHASE_TAIL(4)

    // P3: A q3; write A(t+1) -> cur^1; counted vmcnt
    READ_FA(6)
    if (t < 7) { WRITE_A() }
    if (t < 6) asm volatile("s_waitcnt vmcnt(4)" ::: "memory");
    else       asm volatile("s_waitcnt vmcnt(0)" ::: "memory");
    PHASE_TAIL(6)

    cur ^= 1;
  }

  // ---- epilogue ----
  const int ld = dlayer[0];
  const float* bias = ((MODE == 0 && pair) ? bias1 : bias0) +
                      ((size_t)ld * NR + role) * HD + n0;
  short* outS = (MODE == 0 && pair) ? outS1 : outS0;

  int pg[8][4];
  if constexpr (MODE == 2) {
#pragma unroll
    for (int mi = 0; mi < 8; ++mi)
#pragma unroll
      for (int j = 0; j < 4; ++j) {
        const int rr = m0 + wr * 128 + mi * 16 + ku * 4 + j;
        pg[mi][j] = scat ? perm[rr] : rr;
      }
  }

#pragma unroll
  for (int ni = 0; ni < 4; ++ni) {
    const int col = wc * 64 + ni * 16 + krow;
    const float b = bias[col];
#pragma unroll
    for (int mi = 0; mi < 8; ++mi) {
      const int rbase = m0 + wr * 128 + mi * 16 + ku * 4;
#pragma unroll
      for (int j = 0; j < 4; ++j) {
        float val = acc[mi][ni][j] + b;
        if constexpr (MODE == 0) {
          outS[(size_t)(rbase + j) * HD + n0 + col] = (short)f2bf(val);
        } else if constexpr (MODE == 1) {
          val = fmaxf(val, 0.f);
          outS[(size_t)(rbase + j) * HD + n0 + col] = (short)f2bf(val);
        } else {
          outF[(size_t)pg[mi][j] * HD + n0 + col] = val;
        }
      }
    }
  }
#undef ISSUE_A
#undef WRITE_A
#undef STAGE_B
#undef READ_FA
#undef PHASE_TAIL
}

// ---------------- launch ----------------

extern "C" void kernel_launch(void* const* d_in, const int* in_sizes, int n_in,
                              void* d_out, int out_size, void* d_ws, size_t ws_size,
                              hipStream_t stream) {
  const float* v    = (const float*)d_in[0];
  const float* r    = (const float*)d_in[1];
  const int*   rol  = (const int*)d_in[2];
  const float* W    = (const float*)d_in[3];
  const float* Wb   = (const float*)d_in[4];
  const float* U    = (const float*)d_in[5];
  const float* Ub   = (const float*)d_in[6];
  const float* P1   = (const float*)d_in[7];
  const float* P1b  = (const float*)d_in[8];
  const float* P2   = (const float*)d_in[9];
  const float* P2b  = (const float*)d_in[10];
  const int*   dly  = (const int*)d_in[11];

  char* ws = (char*)d_ws;
  int* ctrl = (int*)ws;                          // 256 B
  int* perm = (int*)(ws + 256);                  // EPAD_MAX ints -> 134,400
  short* Wbf = (short*)(ws + 134400);            // 4 x NR*HD*HD bf16
  short* Ubf  = Wbf + (size_t)NR * HD * HD;      // -> 3,280,128
  short* P1bf = Ubf + (size_t)NR * HD * HD;      // -> 4,852,992
  short* P2bf = P1bf + (size_t)NR * HD * HD;     // -> 6,425,856
  short* vp = (short*)(ws + 6425856);            // EPAD_MAX*HD bf16
  short* rp = vp + (size_t)EPAD_MAX * HD;        // -> 75,107,584
  float* out = (float*)d_out;

  const bool bigws = ws_size >= 109448448ull;
  short* tb = bigws ? (short*)(ws + 75107584) : (short*)d_out;  // 34.3 MB
  float* outs = (float*)(ws + 6425856);          // fallback sorted f32 (over vp+rp)

  k_sort1<<<1, 1024, 0, stream>>>(rol, ctrl);
  k_scatter<<<E_TOT / 256, 256, 0, stream>>>(rol, ctrl, perm);
  k_padfill<<<1, 256, 0, stream>>>(ctrl, perm);
  k_convw<<<dim3((NR * HD * HD) / 4 / 256, 4, 1), 256, 0, stream>>>(W, U, P1, P2, dly, Wbf);

  k_gemm<0><<<NBG0, 512, 0, stream>>>(v, r, Wbf, Ubf, Wb, Ub, dly, ctrl, perm,
                                      nullptr, vp, rp, 0);
  k_gemm<1><<<NBG1, 512, 0, stream>>>(vp, rp, P1bf, nullptr, P1b, nullptr, dly, ctrl, perm,
                                      nullptr, tb, nullptr, 0);
  k_gemm<2><<<NBG1, 512, 0, stream>>>(tb, nullptr, P2bf, nullptr, P2b, nullptr, dly, ctrl, perm,
                                      bigws ? out : outs, nullptr, nullptr, bigws ? 1 : 0);
  if (!bigws)
    k_unsort<<<EPAD_MAX * 128 / 256, 256, 0, stream>>>(outs, perm, ctrl, out);

  (void)in_sizes; (void)n_in; (void)out_size;
}